// Round 1
// baseline (1315.794 us; speedup 1.0000x reference)
//
#include <hip/hip_runtime.h>
#include <stdint.h>

// TopK similarity: 4096 queries x (4096 rows x 128 vecs x 128 dim), top-16 rows.
// K0 fp32->bf16 table | K1 bf16 32x32x16 MFMA coarse per-row max + chunk top-8
// (wave owns 64 queries = 2 B-fragment sets so each LDS A-read feeds 2 MFMAs;
// whole row staged via global_load_lds w/ source-side XOR swizzle,
// double-buffered; top-8 kept per-lane in registers) |
// K2 wave-per-query merge -> top-24 rows + row buckets | K3 exact fp32 refine
// per row-bucket, 4 entries batched per vector-thread (LDS read amortized 4x,
// per-dot fp32 order unchanged) | K4 sort + gather outputs.
// ws assumption: >= ~209 MiB.

typedef __attribute__((ext_vector_type(8))) short short8;
typedef __attribute__((ext_vector_type(4))) float floatx4;
typedef __attribute__((ext_vector_type(16))) float floatx16;
typedef unsigned long long u64;
typedef unsigned int u32;

#define NQ 4096
#define NR 4096
#define NV 128
#define ND 128
#define KTOP 16
#define RC 16            // rows per coarse chunk
#define NCHUNK (NR / RC) // 256
#define CPC 8            // candidates kept per (query, chunk)
#define CSEL 24          // refined candidates per query
#define BCAP 1024        // bucket capacity per table row

__device__ __forceinline__ unsigned short f2bf(float f) {
  u32 u = __float_as_uint(f);
  u32 r = u + 0x7FFFu + ((u >> 16) & 1u); // round-to-nearest-even
  return (unsigned short)(r >> 16);
}
__device__ __forceinline__ u32 key_of(float s) { // monotone float->u32
  u32 b = __float_as_uint(s);
  return (b & 0x80000000u) ? ~b : (b | 0x80000000u);
}
__device__ __forceinline__ float unkey(u32 k) {
  u32 b = (k & 0x80000000u) ? (k & 0x7FFFFFFFu) : ~k;
  return __uint_as_float(b);
}
__device__ __forceinline__ void glds16(const void* g, void* l) {
  __builtin_amdgcn_global_load_lds(
      (const __attribute__((address_space(1))) unsigned int*)g,
      (__attribute__((address_space(3))) unsigned int*)l, 16, 0, 0);
}
__device__ __forceinline__ float max16(floatx16 a) { // log-depth (v_max3-friendly)
  float m0 = fmaxf(fmaxf(a[0], a[1]), fmaxf(a[2], a[3]));
  float m1 = fmaxf(fmaxf(a[4], a[5]), fmaxf(a[6], a[7]));
  float m2 = fmaxf(fmaxf(a[8], a[9]), fmaxf(a[10], a[11]));
  float m3 = fmaxf(fmaxf(a[12], a[13]), fmaxf(a[14], a[15]));
  return fmaxf(fmaxf(m0, m1), fmaxf(m2, m3));
}
__device__ __forceinline__ void insert8(u64* a, u64 x) { // sorted-desc bubble
  if (x > a[CPC - 1]) {
#pragma unroll
    for (int p = 0; p < CPC; p++) {
      u64 mx = a[p] > x ? a[p] : x;
      u64 mn = a[p] > x ? x : a[p];
      a[p] = mx; x = mn;
    }
  }
}

// ---------------- K0: table fp32 -> bf16 ----------------
__global__ void k0_convert(const float* __restrict__ t, unsigned short* __restrict__ o) {
  size_t i = ((size_t)blockIdx.x * 256 + threadIdx.x) * 4;
  float4 v = *reinterpret_cast<const float4*>(t + i);
  ushort4 r;
  r.x = f2bf(v.x); r.y = f2bf(v.y); r.z = f2bf(v.z); r.w = f2bf(v.w);
  *reinterpret_cast<ushort4*>(o + i) = r;
}

// ---------------- K1: coarse MFMA per-row max + chunk top-8 ------------------
// Grid (16 qblocks, 256 chunks), 256 threads. Wave w owns queries
// w*64..w*64+63 (two 32-query B-fragment sets, 64 VGPRs) so each LDS A-read
// feeds TWO MFMAs (ds_read_b128:MFMA = 1:2) and the two accumulator chains
// are independent. Row staged to LDS by global_load_lds (16B), XOR swizzle
// applied on the GLOBAL source address, double-buffered.
__launch_bounds__(256, 2)
__global__ void k1_coarse(const float* __restrict__ Q, const unsigned short* __restrict__ T16,
                          u64* __restrict__ cand) {
  __shared__ short Blds[2][128 * 128]; // 2 x 32 KiB

  const int tid = threadIdx.x;
  const int wave = tid >> 6;
  const int lane = tid & 63;
  const int l31 = lane & 31;
  const int l15 = lane & 15;
  const int half = lane >> 5;
  const int qblock = blockIdx.x; // 0..15
  const int chunk = blockIdx.y;

  // B fragments: 64 queries of this wave (2 sets of 32).
  // B[n=lane&31][k=(lane>>5)*8+j], K=16/frag.
  short8 bf0[8], bf1[8];
  {
    const float* qp0 = Q + (size_t)(qblock * 256 + wave * 64 + l31) * 128;
    const float* qp1 = qp0 + 32 * 128;
#pragma unroll
    for (int kb = 0; kb < 8; kb++) {
      float4 x = *reinterpret_cast<const float4*>(qp0 + kb * 16 + half * 8);
      float4 y = *reinterpret_cast<const float4*>(qp0 + kb * 16 + half * 8 + 4);
      short8 b;
      b[0] = (short)f2bf(x.x); b[1] = (short)f2bf(x.y);
      b[2] = (short)f2bf(x.z); b[3] = (short)f2bf(x.w);
      b[4] = (short)f2bf(y.x); b[5] = (short)f2bf(y.y);
      b[6] = (short)f2bf(y.z); b[7] = (short)f2bf(y.w);
      bf0[kb] = b;
      x = *reinterpret_cast<const float4*>(qp1 + kb * 16 + half * 8);
      y = *reinterpret_cast<const float4*>(qp1 + kb * 16 + half * 8 + 4);
      b[0] = (short)f2bf(x.x); b[1] = (short)f2bf(x.y);
      b[2] = (short)f2bf(x.z); b[3] = (short)f2bf(x.w);
      b[4] = (short)f2bf(y.x); b[5] = (short)f2bf(y.y);
      b[6] = (short)f2bf(y.z); b[7] = (short)f2bf(y.w);
      bf1[kb] = b;
    }
  }

  // Per-lane glds source byte-offsets within a row. Issue i: LDS slot
  // (wave*8+i)*1024B + lane*16B = short index s; v=s>>7, blk8'=(s>>3)&15;
  // source blk8 = blk8' ^ (v&15) -> conflict-free MFMA reads later.
  int goff[8];
#pragma unroll
  for (int i = 0; i < 8; i++) {
    int v = wave * 32 + i * 4 + (lane >> 4);
    int kb = l15 ^ (v & 15);
    goff[i] = v * 256 + kb * 16; // bytes
  }
  const char* chunkbase = (const char*)(T16 + (size_t)(chunk * RC) * (NV * ND));

  // stage row 0 into buf 0
#pragma unroll
  for (int i = 0; i < 8; i++)
    glds16(chunkbase + goff[i], &Blds[0][(wave * 8 + i) * 512 + lane * 8]);
  __syncthreads();

  u64 a0[CPC], a1[CPC]; // per-lane top-8 for the two owned queries
#pragma unroll
  for (int i = 0; i < CPC; i++) { a0[i] = 0; a1[i] = 0; }

  const short* abase = &Blds[0][l31 * 128];
  for (int rl = 0; rl < RC; rl++) {
    const int cur = rl & 1;
    if (rl < RC - 1) { // async stage next row into other buffer
      const char* rs = chunkbase + (size_t)(rl + 1) * 32768;
#pragma unroll
      for (int i = 0; i < 8; i++)
        glds16(rs + goff[i], &Blds[1 - cur][(wave * 8 + i) * 512 + lane * 8]);
    }

    float run0 = -3.402823466e+38f, run1 = -3.402823466e+38f;
#pragma unroll
    for (int t = 0; t < 4; t++) {
      floatx16 acc0 = 0, acc1 = 0;
#pragma unroll
      for (int kb = 0; kb < 8; kb++) {
        // A[m=lane&31 -> vector t*32+l31][k=half*8+j]; swizzled block index
        const short* ap = abase + cur * 16384 + t * 4096 +
                          8 * ((kb * 2 + half) ^ (l31 & 15));
        short8 af = *reinterpret_cast<const short8*>(ap);
        acc0 = __builtin_amdgcn_mfma_f32_32x32x16_bf16(af, bf0[kb], acc0, 0, 0, 0);
        acc1 = __builtin_amdgcn_mfma_f32_32x32x16_bf16(af, bf1[kb], acc1, 0, 0, 0);
      }
      run0 = fmaxf(run0, max16(acc0));
      run1 = fmaxf(run1, max16(acc1));
    }
    run0 = fmaxf(run0, __shfl_xor(run0, 32, 64)); // merge the two v-halves
    run1 = fmaxf(run1, __shfl_xor(run1, 32, 64));

    u32 rid = (u32)(chunk * RC + rl);
    insert8(a0, ((u64)key_of(run0) << 32) | rid);
    insert8(a1, ((u64)key_of(run1) << 32) | rid);
    __syncthreads(); // drains glds (issued a full row ago) + guards buffer swap
  }

  if (lane < 32) { // lane owns the two queries; halves are duplicates
    const int q0 = qblock * 256 + wave * 64 + l31;
    u64* dst0 = cand + (size_t)q0 * (NCHUNK * CPC) + chunk * CPC;
    u64* dst1 = dst0 + (size_t)32 * (NCHUNK * CPC);
#pragma unroll
    for (int i = 0; i < CPC; i++) { dst0[i] = a0[i]; dst1[i] = a1[i]; }
  }
}

// ---------------- K2: wave-per-query merge -> top-24 rows + buckets ----------
__global__ void k2_select(const u64* __restrict__ cand, u64* __restrict__ refined,
                          u32* __restrict__ cnt, u32* __restrict__ bucket) {
  const int q = blockIdx.x;
  const int lane = threadIdx.x;
  const u64* base = cand + (size_t)q * (NCHUNK * CPC);
  u64 a[12];
#pragma unroll
  for (int i = 0; i < 12; i++) a[i] = 0;
  for (int i = 0; i < 32; i++) {
    u64 x = base[i * 64 + lane];
    if (x > a[11]) {
#pragma unroll
      for (int p = 0; p < 12; p++) {
        u64 mx = a[p] > x ? a[p] : x;
        u64 mn = a[p] > x ? x : a[p];
        a[p] = mx; x = mn;
      }
    }
  }
  if (lane < CSEL) refined[(size_t)q * CSEL + lane] = 0; // sentinel for K3

  for (int j = 0; j < CSEL; j++) {
    u64 head = a[0];
    u64 W = head;
#pragma unroll
    for (int off = 1; off < 64; off <<= 1) {
      u64 o = __shfl_xor(W, off, 64);
      if (o > W) W = o;
    }
    if (head == W) { // unique winner lane: pop + emit bucket entry
#pragma unroll
      for (int p = 0; p < 11; p++) a[p] = a[p + 1];
      a[11] = 0;
      u32 row = (u32)W & 4095u;
      u32 slot = atomicAdd(cnt + row, 1u);
      if (slot < BCAP) bucket[(size_t)row * BCAP + slot] = ((u32)q << 5) | (u32)j;
    }
  }
}

// ---------------- K3: exact fp32 refine, bucketed by table row ---------------
// Grid 4096 (one WG per row), 256 threads = 2 vector-groups of 128; each group
// processes FOUR entries per pass (each LDS float4 read feeds 16 fmas). Row in
// swizzled LDS (64 KiB); q scalarized via readfirstlane -> s_loads. Per-dot
// fp32 accumulation order is strictly sequential (matches ref exactly).
__device__ __forceinline__ void k3_emit(float acc, u32 ent, int row, int v, int lane,
                                        u64* __restrict__ refined) {
  // wave argmax (smaller v wins ties), then global atomicMax
  u64 p = ((u64)key_of(acc) << 32) | (u32)(127 - v);
#pragma unroll
  for (int off = 1; off < 64; off <<= 1) {
    u64 o = __shfl_xor(p, off, 64);
    if (o > p) p = o;
  }
  if (lane == 0) {
    u32 q = ent >> 5, j = ent & 31u;
    u32 vbest = 127u - (u32)(p & 0xFFFFFFFFu);
    u64 packed = ((p >> 32) << 32) | (u32)(row * 128 + vbest);
    atomicMax(reinterpret_cast<unsigned long long*>(&refined[(size_t)q * CSEL + j]), packed);
  }
}

__global__ void k3_refine(const float* __restrict__ Q, const float* __restrict__ table,
                          const u32* __restrict__ cnt, const u32* __restrict__ bucket,
                          u64* __restrict__ refined) {
  __shared__ float rowv[128 * 128]; // float4 chunk d4 of vec v at (d4 ^ (v&31))
  const int row = blockIdx.x;
  const int tid = threadIdx.x; // 0..255
  u32 n = cnt[row];
  if (n > BCAP) n = BCAP;
  if (n == 0) return;
  const float* src = table + (size_t)row * (NV * ND);
#pragma unroll
  for (int i = 0; i < 16; i++) {
    int idx = i * 1024 + tid * 4;
    int v = idx >> 7;
    int d4 = tid & 31;
    *reinterpret_cast<float4*>(&rowv[v * 128 + ((d4 ^ (v & 31)) << 2)]) =
        *reinterpret_cast<const float4*>(src + idx);
  }
  __syncthreads();
  const int g = tid >> 7;   // entry-group 0/1
  const int v = tid & 127;  // vector owned by this thread
  const int lane = tid & 63;
  const int sw = v & 31;
  const u32* bk = bucket + (size_t)row * BCAP;
  for (u32 e0 = (u32)(g * 4); e0 < n; e0 += 8) {
    // clamp OOB batch slots to a valid entry; their atomic is guarded below
    u32 ent0 = __builtin_amdgcn_readfirstlane(bk[e0]);
    u32 ent1 = __builtin_amdgcn_readfirstlane(bk[e0 + 1 < n ? e0 + 1 : e0]);
    u32 ent2 = __builtin_amdgcn_readfirstlane(bk[e0 + 2 < n ? e0 + 2 : e0]);
    u32 ent3 = __builtin_amdgcn_readfirstlane(bk[e0 + 3 < n ? e0 + 3 : e0]);
    const float* qp0 = Q + (size_t)(ent0 >> 5) * 128; // uniform -> scalar loads
    const float* qp1 = Q + (size_t)(ent1 >> 5) * 128;
    const float* qp2 = Q + (size_t)(ent2 >> 5) * 128;
    const float* qp3 = Q + (size_t)(ent3 >> 5) * 128;
    float c0 = 0.f, c1 = 0.f, c2 = 0.f, c3 = 0.f;
#pragma unroll
    for (int d4 = 0; d4 < 32; d4++) { // strict sequential order per dot
      float4 rv = *reinterpret_cast<const float4*>(&rowv[v * 128 + ((d4 ^ sw) << 2)]);
      c0 = fmaf(rv.x, qp0[d4 * 4 + 0], c0);
      c0 = fmaf(rv.y, qp0[d4 * 4 + 1], c0);
      c0 = fmaf(rv.z, qp0[d4 * 4 + 2], c0);
      c0 = fmaf(rv.w, qp0[d4 * 4 + 3], c0);
      c1 = fmaf(rv.x, qp1[d4 * 4 + 0], c1);
      c1 = fmaf(rv.y, qp1[d4 * 4 + 1], c1);
      c1 = fmaf(rv.z, qp1[d4 * 4 + 2], c1);
      c1 = fmaf(rv.w, qp1[d4 * 4 + 3], c1);
      c2 = fmaf(rv.x, qp2[d4 * 4 + 0], c2);
      c2 = fmaf(rv.y, qp2[d4 * 4 + 1], c2);
      c2 = fmaf(rv.z, qp2[d4 * 4 + 2], c2);
      c2 = fmaf(rv.w, qp2[d4 * 4 + 3], c2);
      c3 = fmaf(rv.x, qp3[d4 * 4 + 0], c3);
      c3 = fmaf(rv.y, qp3[d4 * 4 + 1], c3);
      c3 = fmaf(rv.z, qp3[d4 * 4 + 2], c3);
      c3 = fmaf(rv.w, qp3[d4 * 4 + 3], c3);
    }
    k3_emit(c0, ent0, row, v, lane, refined);
    if (e0 + 1 < n) k3_emit(c1, ent1, row, v, lane, refined);
    if (e0 + 2 < n) k3_emit(c2, ent2, row, v, lane, refined);
    if (e0 + 3 < n) k3_emit(c3, ent3, row, v, lane, refined);
  }
}

// ---------------- K4: sort 24 -> top-16, gather values/scores/ids ------------
__global__ void k4_finalize(const float* __restrict__ table, const u64* __restrict__ refined,
                            float* __restrict__ out) {
  __shared__ u64 arr[CSEL];
  __shared__ u32 fids[KTOP];
  __shared__ float scs[KTOP];
  const int q = blockIdx.x;
  const int tid = threadIdx.x;
  if (tid < CSEL) arr[tid] = refined[(size_t)q * CSEL + tid];
  __syncthreads();
  if (tid == 0) {
    for (int i = 1; i < CSEL; i++) { // insertion sort desc = ref order
      u64 x = arr[i]; int p = i;
      while (p > 0 && arr[p - 1] < x) { arr[p] = arr[p - 1]; p--; }
      arr[p] = x;
    }
    for (int i = 0; i < KTOP; i++) {
      fids[i] = (u32)arr[i];
      scs[i] = unkey((u32)(arr[i] >> 32));
    }
  }
  __syncthreads();
  const int i = tid >> 4, sub = tid & 15;
  const float* src = table + (size_t)fids[i] * 128 + sub * 8;
  float* dst = out + ((size_t)q * KTOP + i) * 128 + sub * 8;
  *reinterpret_cast<float4*>(dst) = *reinterpret_cast<const float4*>(src);
  *reinterpret_cast<float4*>(dst + 4) = *reinterpret_cast<const float4*>(src + 4);
  if (tid < KTOP) {
    out[8388608 + (size_t)q * KTOP + tid] = scs[tid];
    out[8388608 + 65536 + (size_t)q * KTOP + tid] = (float)fids[tid];
  }
}

extern "C" void kernel_launch(void* const* d_in, const int* in_sizes, int n_in,
                              void* d_out, int out_size, void* d_ws, size_t ws_size,
                              hipStream_t stream) {
  (void)in_sizes; (void)n_in; (void)out_size; (void)ws_size;
  const float* Q = (const float*)d_in[0];
  const float* T = (const float*)d_in[1];
  float* out = (float*)d_out;
  char* ws = (char*)d_ws;
  // ws layout (total ~209 MiB)
  unsigned short* T16 = (unsigned short*)ws;                                   // 128 MiB
  u64* cand    = (u64*)(ws + 134217728);                                       //  64 MiB
  u32* cnt     = (u32*)(ws + 134217728 + 67108864);                            //  16 KiB
  u32* bucket  = (u32*)(ws + 134217728 + 67108864 + 16384);                    //  16 MiB
  u64* refined = (u64*)(ws + 134217728 + 67108864 + 16384 + 16777216);         // 768 KiB

  hipMemsetAsync(cnt, 0, NR * sizeof(u32), stream);
  k0_convert<<<65536, 256, 0, stream>>>(T, T16);
  k1_coarse<<<dim3(16, 256), 256, 0, stream>>>(Q, T16, cand);
  k2_select<<<NQ, 64, 0, stream>>>(cand, refined, cnt, bucket);
  k3_refine<<<NR, 256, 0, stream>>>(Q, T, cnt, bucket, refined);
  k4_finalize<<<NQ, 256, 0, stream>>>(T, refined, out);
}

// Round 3
// 1183.550 us; speedup vs baseline: 1.1117x; 1.1117x over previous
//
#include <hip/hip_runtime.h>
#include <stdint.h>

// TopK similarity: 4096 queries x (4096 rows x 128 vecs x 128 dim), top-16 rows.
// K0 fp32->bf16 table | K1 bf16 32x32x16 MFMA coarse per-row max + chunk top-8
// (R1-verified geometry: 256 thr / 4 waves, wave owns 64 queries = 2 B-frag
// sets so each LDS A-read feeds 2 MFMAs; row staged via global_load_lds w/
// source-side XOR swizzle, double-buffered; + s_setprio around MFMA cluster) |
// K2 wave-per-query merge -> top-24 rows + row buckets | K3 exact fp32 refine
// per row-bucket (R0-verified: 512 thr, scalarized q, atomicMax) |
// K4 sort + gather outputs.  ws assumption: >= ~209 MiB.

typedef __attribute__((ext_vector_type(8))) short short8;
typedef __attribute__((ext_vector_type(4))) float floatx4;
typedef __attribute__((ext_vector_type(16))) float floatx16;
typedef unsigned long long u64;
typedef unsigned int u32;

#define NQ 4096
#define NR 4096
#define NV 128
#define ND 128
#define KTOP 16
#define RC 16            // rows per coarse chunk
#define NCHUNK (NR / RC) // 256
#define CPC 8            // candidates kept per (query, chunk)
#define CSEL 24          // refined candidates per query
#define BCAP 1024        // bucket capacity per table row

__device__ __forceinline__ unsigned short f2bf(float f) {
  u32 u = __float_as_uint(f);
  u32 r = u + 0x7FFFu + ((u >> 16) & 1u); // round-to-nearest-even
  return (unsigned short)(r >> 16);
}
__device__ __forceinline__ u32 key_of(float s) { // monotone float->u32
  u32 b = __float_as_uint(s);
  return (b & 0x80000000u) ? ~b : (b | 0x80000000u);
}
__device__ __forceinline__ float unkey(u32 k) {
  u32 b = (k & 0x80000000u) ? (k & 0x7FFFFFFFu) : ~k;
  return __uint_as_float(b);
}
__device__ __forceinline__ void glds16(const void* g, void* l) {
  __builtin_amdgcn_global_load_lds(
      (const __attribute__((address_space(1))) unsigned int*)g,
      (__attribute__((address_space(3))) unsigned int*)l, 16, 0, 0);
}
__device__ __forceinline__ float max16(floatx16 a) { // log-depth fmax tree
  float m0 = fmaxf(fmaxf(a[0], a[1]), fmaxf(a[2], a[3]));
  float m1 = fmaxf(fmaxf(a[4], a[5]), fmaxf(a[6], a[7]));
  float m2 = fmaxf(fmaxf(a[8], a[9]), fmaxf(a[10], a[11]));
  float m3 = fmaxf(fmaxf(a[12], a[13]), fmaxf(a[14], a[15]));
  return fmaxf(fmaxf(m0, m1), fmaxf(m2, m3));
}
__device__ __forceinline__ void insert8(u64* a, u64 x) { // sorted-desc bubble
  if (x > a[CPC - 1]) {
#pragma unroll
    for (int p = 0; p < CPC; p++) {
      u64 mx = a[p] > x ? a[p] : x;
      u64 mn = a[p] > x ? x : a[p];
      a[p] = mx; x = mn;
    }
  }
}

// ---------------- K0: table fp32 -> bf16 ----------------
__global__ void k0_convert(const float* __restrict__ t, unsigned short* __restrict__ o) {
  size_t i = ((size_t)blockIdx.x * 256 + threadIdx.x) * 4;
  float4 v = *reinterpret_cast<const float4*>(t + i);
  ushort4 r;
  r.x = f2bf(v.x); r.y = f2bf(v.y); r.z = f2bf(v.z); r.w = f2bf(v.w);
  *reinterpret_cast<ushort4*>(o + i) = r;
}

// ---------------- K1: coarse MFMA per-row max + chunk top-8 ------------------
// Grid (16 qblocks, 256 chunks), 256 threads. Wave w owns queries
// w*64..w*64+63 (two 32-query B-fragment sets, 64 VGPRs) so each LDS A-read
// feeds TWO MFMAs (ds_read_b128:MFMA = 1:2) and the two accumulator chains
// are independent. Row staged to LDS by global_load_lds (16B), XOR swizzle
// applied on the GLOBAL source address, double-buffered.
__launch_bounds__(256, 2)
__global__ void k1_coarse(const float* __restrict__ Q, const unsigned short* __restrict__ T16,
                          u64* __restrict__ cand) {
  __shared__ short Blds[2][128 * 128]; // 2 x 32 KiB

  const int tid = threadIdx.x;
  const int wave = tid >> 6;
  const int lane = tid & 63;
  const int l31 = lane & 31;
  const int l15 = lane & 15;
  const int half = lane >> 5;
  const int qblock = blockIdx.x; // 0..15
  const int chunk = blockIdx.y;

  // B fragments: 64 queries of this wave (2 sets of 32).
  // B[n=lane&31][k=(lane>>5)*8+j], K=16/frag.
  short8 bf0[8], bf1[8];
  {
    const float* qp0 = Q + (size_t)(qblock * 256 + wave * 64 + l31) * 128;
    const float* qp1 = qp0 + 32 * 128;
#pragma unroll
    for (int kb = 0; kb < 8; kb++) {
      float4 x = *reinterpret_cast<const float4*>(qp0 + kb * 16 + half * 8);
      float4 y = *reinterpret_cast<const float4*>(qp0 + kb * 16 + half * 8 + 4);
      short8 b;
      b[0] = (short)f2bf(x.x); b[1] = (short)f2bf(x.y);
      b[2] = (short)f2bf(x.z); b[3] = (short)f2bf(x.w);
      b[4] = (short)f2bf(y.x); b[5] = (short)f2bf(y.y);
      b[6] = (short)f2bf(y.z); b[7] = (short)f2bf(y.w);
      bf0[kb] = b;
      x = *reinterpret_cast<const float4*>(qp1 + kb * 16 + half * 8);
      y = *reinterpret_cast<const float4*>(qp1 + kb * 16 + half * 8 + 4);
      b[0] = (short)f2bf(x.x); b[1] = (short)f2bf(x.y);
      b[2] = (short)f2bf(x.z); b[3] = (short)f2bf(x.w);
      b[4] = (short)f2bf(y.x); b[5] = (short)f2bf(y.y);
      b[6] = (short)f2bf(y.z); b[7] = (short)f2bf(y.w);
      bf1[kb] = b;
    }
  }

  // Per-lane glds source byte-offsets within a row. Issue i: LDS slot
  // (wave*8+i)*1024B + lane*16B = short index s; v=s>>7, blk8'=(s>>3)&15;
  // source blk8 = blk8' ^ (v&15) -> conflict-free MFMA reads later.
  int goff[8];
#pragma unroll
  for (int i = 0; i < 8; i++) {
    int v = wave * 32 + i * 4 + (lane >> 4);
    int kb = l15 ^ (v & 15);
    goff[i] = v * 256 + kb * 16; // bytes
  }
  const char* chunkbase = (const char*)(T16 + (size_t)(chunk * RC) * (NV * ND));

  // stage row 0 into buf 0
#pragma unroll
  for (int i = 0; i < 8; i++)
    glds16(chunkbase + goff[i], &Blds[0][(wave * 8 + i) * 512 + lane * 8]);
  __syncthreads();

  u64 a0[CPC], a1[CPC]; // per-lane top-8 for the two owned queries
#pragma unroll
  for (int i = 0; i < CPC; i++) { a0[i] = 0; a1[i] = 0; }

  const short* abase = &Blds[0][l31 * 128];
  for (int rl = 0; rl < RC; rl++) {
    const int cur = rl & 1;
    if (rl < RC - 1) { // async stage next row into other buffer
      const char* rs = chunkbase + (size_t)(rl + 1) * 32768;
#pragma unroll
      for (int i = 0; i < 8; i++)
        glds16(rs + goff[i], &Blds[1 - cur][(wave * 8 + i) * 512 + lane * 8]);
    }

    float run0 = -3.402823466e+38f, run1 = -3.402823466e+38f;
#pragma unroll
    for (int t = 0; t < 4; t++) {
      floatx16 acc0 = 0, acc1 = 0;
      __builtin_amdgcn_s_setprio(1);
#pragma unroll
      for (int kb = 0; kb < 8; kb++) {
        // A[m=lane&31 -> vector t*32+l31][k=half*8+j]; swizzled block index
        const short* ap = abase + cur * 16384 + t * 4096 +
                          8 * ((kb * 2 + half) ^ (l31 & 15));
        short8 af = *reinterpret_cast<const short8*>(ap);
        acc0 = __builtin_amdgcn_mfma_f32_32x32x16_bf16(af, bf0[kb], acc0, 0, 0, 0);
        acc1 = __builtin_amdgcn_mfma_f32_32x32x16_bf16(af, bf1[kb], acc1, 0, 0, 0);
      }
      __builtin_amdgcn_s_setprio(0);
      run0 = fmaxf(run0, max16(acc0));
      run1 = fmaxf(run1, max16(acc1));
    }
    run0 = fmaxf(run0, __shfl_xor(run0, 32, 64)); // merge the two v-halves
    run1 = fmaxf(run1, __shfl_xor(run1, 32, 64));

    u32 rid = (u32)(chunk * RC + rl);
    insert8(a0, ((u64)key_of(run0) << 32) | rid);
    insert8(a1, ((u64)key_of(run1) << 32) | rid);
    __syncthreads(); // drains glds (issued a full row ago) + guards buffer swap
  }

  if (lane < 32) { // lane owns the two queries; halves are duplicates
    const int q0 = qblock * 256 + wave * 64 + l31;
    u64* dst0 = cand + (size_t)q0 * (NCHUNK * CPC) + chunk * CPC;
    u64* dst1 = dst0 + (size_t)32 * (NCHUNK * CPC);
#pragma unroll
    for (int i = 0; i < CPC; i++) { dst0[i] = a0[i]; dst1[i] = a1[i]; }
  }
}

// ---------------- K2: wave-per-query merge -> top-24 rows + buckets ----------
__global__ void k2_select(const u64* __restrict__ cand, u64* __restrict__ refined,
                          u32* __restrict__ cnt, u32* __restrict__ bucket) {
  const int q = blockIdx.x;
  const int lane = threadIdx.x;
  const u64* base = cand + (size_t)q * (NCHUNK * CPC);
  u64 a[12];
#pragma unroll
  for (int i = 0; i < 12; i++) a[i] = 0;
  for (int i = 0; i < 32; i++) {
    u64 x = base[i * 64 + lane];
    if (x > a[11]) {
#pragma unroll
      for (int p = 0; p < 12; p++) {
        u64 mx = a[p] > x ? a[p] : x;
        u64 mn = a[p] > x ? x : a[p];
        a[p] = mx; x = mn;
      }
    }
  }
  if (lane < CSEL) refined[(size_t)q * CSEL + lane] = 0; // sentinel for K3

  for (int j = 0; j < CSEL; j++) {
    u64 head = a[0];
    u64 W = head;
#pragma unroll
    for (int off = 1; off < 64; off <<= 1) {
      u64 o = __shfl_xor(W, off, 64);
      if (o > W) W = o;
    }
    if (head == W) { // unique winner lane: pop + emit bucket entry
#pragma unroll
      for (int p = 0; p < 11; p++) a[p] = a[p + 1];
      a[11] = 0;
      u32 row = (u32)W & 4095u;
      u32 slot = atomicAdd(cnt + row, 1u);
      if (slot < BCAP) bucket[(size_t)row * BCAP + slot] = ((u32)q << 5) | (u32)j;
    }
  }
}

// ---------------- K3: exact fp32 refine, bucketed by table row ---------------
// Grid 4096 (one WG per row), 512 threads (4 entries in flight). Row in
// swizzled LDS (64 KiB); q scalarized via readfirstlane -> s_loads.
__global__ void k3_refine(const float* __restrict__ Q, const float* __restrict__ table,
                          const u32* __restrict__ cnt, const u32* __restrict__ bucket,
                          u64* __restrict__ refined) {
  __shared__ float rowv[128 * 128]; // float4 chunk d4 of vec v at (d4 ^ (v&31))
  const int row = blockIdx.x;
  const int tid = threadIdx.x; // 0..511
  u32 n = cnt[row];
  if (n > BCAP) n = BCAP;
  if (n == 0) return;
  const float* src = table + (size_t)row * (NV * ND);
#pragma unroll
  for (int i = 0; i < 8; i++) {
    int idx = i * 2048 + tid * 4;
    int v = idx >> 7;
    int d4 = tid & 31;
    *reinterpret_cast<float4*>(&rowv[v * 128 + ((d4 ^ (v & 31)) << 2)]) =
        *reinterpret_cast<const float4*>(src + idx);
  }
  __syncthreads();
  const int v = tid & 127; // vector owned by this thread
  const int lane = tid & 63;
  const int sw = v & 31;
  for (u32 ei = (u32)(tid >> 7); ei < n; ei += 4) {
    u32 ent = __builtin_amdgcn_readfirstlane(bucket[(size_t)row * BCAP + ei]);
    u32 q = ent >> 5, j = ent & 31u;
    const float* qp = Q + (size_t)q * 128; // uniform -> scalar loads
    float acc = 0.f;
#pragma unroll
    for (int d4 = 0; d4 < 32; d4++) { // strict sequential order (matches ref)
      float4 rv = *reinterpret_cast<const float4*>(&rowv[v * 128 + ((d4 ^ sw) << 2)]);
      acc = fmaf(rv.x, qp[d4 * 4 + 0], acc);
      acc = fmaf(rv.y, qp[d4 * 4 + 1], acc);
      acc = fmaf(rv.z, qp[d4 * 4 + 2], acc);
      acc = fmaf(rv.w, qp[d4 * 4 + 3], acc);
    }
    // wave argmax (smaller v wins ties), then global atomicMax
    u64 p = ((u64)key_of(acc) << 32) | (u32)(127 - v);
#pragma unroll
    for (int off = 1; off < 64; off <<= 1) {
      u64 o = __shfl_xor(p, off, 64);
      if (o > p) p = o;
    }
    if (lane == 0) {
      u32 vbest = 127u - (u32)(p & 0xFFFFFFFFu);
      u64 packed = ((p >> 32) << 32) | (u32)(row * 128 + vbest);
      atomicMax(reinterpret_cast<unsigned long long*>(&refined[(size_t)q * CSEL + j]), packed);
    }
  }
}

// ---------------- K4: sort 24 -> top-16, gather values/scores/ids ------------
__global__ void k4_finalize(const float* __restrict__ table, const u64* __restrict__ refined,
                            float* __restrict__ out) {
  __shared__ u64 arr[CSEL];
  __shared__ u32 fids[KTOP];
  __shared__ float scs[KTOP];
  const int q = blockIdx.x;
  const int tid = threadIdx.x;
  if (tid < CSEL) arr[tid] = refined[(size_t)q * CSEL + tid];
  __syncthreads();
  if (tid == 0) {
    for (int i = 1; i < CSEL; i++) { // insertion sort desc = ref order
      u64 x = arr[i]; int p = i;
      while (p > 0 && arr[p - 1] < x) { arr[p] = arr[p - 1]; p--; }
      arr[p] = x;
    }
    for (int i = 0; i < KTOP; i++) {
      fids[i] = (u32)arr[i];
      scs[i] = unkey((u32)(arr[i] >> 32));
    }
  }
  __syncthreads();
  const int i = tid >> 4, sub = tid & 15;
  const float* src = table + (size_t)fids[i] * 128 + sub * 8;
  float* dst = out + ((size_t)q * KTOP + i) * 128 + sub * 8;
  *reinterpret_cast<float4*>(dst) = *reinterpret_cast<const float4*>(src);
  *reinterpret_cast<float4*>(dst + 4) = *reinterpret_cast<const float4*>(src + 4);
  if (tid < KTOP) {
    out[8388608 + (size_t)q * KTOP + tid] = scs[tid];
    out[8388608 + 65536 + (size_t)q * KTOP + tid] = (float)fids[tid];
  }
}

extern "C" void kernel_launch(void* const* d_in, const int* in_sizes, int n_in,
                              void* d_out, int out_size, void* d_ws, size_t ws_size,
                              hipStream_t stream) {
  (void)in_sizes; (void)n_in; (void)out_size; (void)ws_size;
  const float* Q = (const float*)d_in[0];
  const float* T = (const float*)d_in[1];
  float* out = (float*)d_out;
  char* ws = (char*)d_ws;
  // ws layout (total ~209 MiB)
  unsigned short* T16 = (unsigned short*)ws;                                   // 128 MiB
  u64* cand    = (u64*)(ws + 134217728);                                       //  64 MiB
  u32* cnt     = (u32*)(ws + 134217728 + 67108864);                            //  16 KiB
  u32* bucket  = (u32*)(ws + 134217728 + 67108864 + 16384);                    //  16 MiB
  u64* refined = (u64*)(ws + 134217728 + 67108864 + 16384 + 16777216);         // 768 KiB

  hipMemsetAsync(cnt, 0, NR * sizeof(u32), stream);
  k0_convert<<<65536, 256, 0, stream>>>(T, T16);
  k1_coarse<<<dim3(16, 256), 256, 0, stream>>>(Q, T16, cand);
  k2_select<<<NQ, 64, 0, stream>>>(cand, refined, cnt, bucket);
  k3_refine<<<NR, 512, 0, stream>>>(Q, T, cnt, bucket, refined);
  k4_finalize<<<NQ, 256, 0, stream>>>(T, refined, out);
}

// Round 4
// 1163.339 us; speedup vs baseline: 1.1310x; 1.0174x over previous
//
#include <hip/hip_runtime.h>
#include <stdint.h>

// TopK similarity: 4096 queries x (4096 rows x 128 vecs x 128 dim), top-16 rows.
// K0 fp32->bf16 table | K1 bf16 32x32x16 MFMA coarse per-row max + chunk top-8
// (R1-verified: 256 thr / 4 waves, wave owns 64 queries = 2 B-frag sets so
// each LDS A-read feeds 2 MFMAs; row staged via global_load_lds w/ source-side
// XOR swizzle, double-buffered; NO setprio — measured -8% in R3) |
// K2 wave-per-query merge -> top-24 rows + row buckets | K3 exact fp32 refine
// per row-bucket (512 thr, 2 entries per thread for chain ILP; strict
// sequential fp32 order per dot preserved) | K4 sort + gather outputs.
// ws assumption: >= ~209 MiB.

typedef __attribute__((ext_vector_type(8))) short short8;
typedef __attribute__((ext_vector_type(4))) float floatx4;
typedef __attribute__((ext_vector_type(16))) float floatx16;
typedef unsigned long long u64;
typedef unsigned int u32;

#define NQ 4096
#define NR 4096
#define NV 128
#define ND 128
#define KTOP 16
#define RC 16            // rows per coarse chunk
#define NCHUNK (NR / RC) // 256
#define CPC 8            // candidates kept per (query, chunk)
#define CSEL 24          // refined candidates per query
#define BCAP 1024        // bucket capacity per table row

__device__ __forceinline__ unsigned short f2bf(float f) {
  u32 u = __float_as_uint(f);
  u32 r = u + 0x7FFFu + ((u >> 16) & 1u); // round-to-nearest-even
  return (unsigned short)(r >> 16);
}
__device__ __forceinline__ u32 key_of(float s) { // monotone float->u32
  u32 b = __float_as_uint(s);
  return (b & 0x80000000u) ? ~b : (b | 0x80000000u);
}
__device__ __forceinline__ float unkey(u32 k) {
  u32 b = (k & 0x80000000u) ? (k & 0x7FFFFFFFu) : ~k;
  return __uint_as_float(b);
}
__device__ __forceinline__ void glds16(const void* g, void* l) {
  __builtin_amdgcn_global_load_lds(
      (const __attribute__((address_space(1))) unsigned int*)g,
      (__attribute__((address_space(3))) unsigned int*)l, 16, 0, 0);
}
__device__ __forceinline__ float max16(floatx16 a) { // log-depth fmax tree
  float m0 = fmaxf(fmaxf(a[0], a[1]), fmaxf(a[2], a[3]));
  float m1 = fmaxf(fmaxf(a[4], a[5]), fmaxf(a[6], a[7]));
  float m2 = fmaxf(fmaxf(a[8], a[9]), fmaxf(a[10], a[11]));
  float m3 = fmaxf(fmaxf(a[12], a[13]), fmaxf(a[14], a[15]));
  return fmaxf(fmaxf(m0, m1), fmaxf(m2, m3));
}
__device__ __forceinline__ void insert8(u64* a, u64 x) { // sorted-desc bubble
  if (x > a[CPC - 1]) {
#pragma unroll
    for (int p = 0; p < CPC; p++) {
      u64 mx = a[p] > x ? a[p] : x;
      u64 mn = a[p] > x ? x : a[p];
      a[p] = mx; x = mn;
    }
  }
}

// ---------------- K0: table fp32 -> bf16 ----------------
__global__ void k0_convert(const float* __restrict__ t, unsigned short* __restrict__ o) {
  size_t i = ((size_t)blockIdx.x * 256 + threadIdx.x) * 4;
  float4 v = *reinterpret_cast<const float4*>(t + i);
  ushort4 r;
  r.x = f2bf(v.x); r.y = f2bf(v.y); r.z = f2bf(v.z); r.w = f2bf(v.w);
  *reinterpret_cast<ushort4*>(o + i) = r;
}

// ---------------- K1: coarse MFMA per-row max + chunk top-8 ------------------
// Grid (16 qblocks, 256 chunks), 256 threads. Wave w owns queries
// w*64..w*64+63 (two 32-query B-fragment sets, 64 VGPRs) so each LDS A-read
// feeds TWO MFMAs (ds_read_b128:MFMA = 1:2) and the two accumulator chains
// are independent. Row staged to LDS by global_load_lds (16B), XOR swizzle
// applied on the GLOBAL source address, double-buffered.
__launch_bounds__(256, 2)
__global__ void k1_coarse(const float* __restrict__ Q, const unsigned short* __restrict__ T16,
                          u64* __restrict__ cand) {
  __shared__ short Blds[2][128 * 128]; // 2 x 32 KiB

  const int tid = threadIdx.x;
  const int wave = tid >> 6;
  const int lane = tid & 63;
  const int l31 = lane & 31;
  const int l15 = lane & 15;
  const int half = lane >> 5;
  const int qblock = blockIdx.x; // 0..15
  const int chunk = blockIdx.y;

  // B fragments: 64 queries of this wave (2 sets of 32).
  // B[n=lane&31][k=(lane>>5)*8+j], K=16/frag.
  short8 bf0[8], bf1[8];
  {
    const float* qp0 = Q + (size_t)(qblock * 256 + wave * 64 + l31) * 128;
    const float* qp1 = qp0 + 32 * 128;
#pragma unroll
    for (int kb = 0; kb < 8; kb++) {
      float4 x = *reinterpret_cast<const float4*>(qp0 + kb * 16 + half * 8);
      float4 y = *reinterpret_cast<const float4*>(qp0 + kb * 16 + half * 8 + 4);
      short8 b;
      b[0] = (short)f2bf(x.x); b[1] = (short)f2bf(x.y);
      b[2] = (short)f2bf(x.z); b[3] = (short)f2bf(x.w);
      b[4] = (short)f2bf(y.x); b[5] = (short)f2bf(y.y);
      b[6] = (short)f2bf(y.z); b[7] = (short)f2bf(y.w);
      bf0[kb] = b;
      x = *reinterpret_cast<const float4*>(qp1 + kb * 16 + half * 8);
      y = *reinterpret_cast<const float4*>(qp1 + kb * 16 + half * 8 + 4);
      b[0] = (short)f2bf(x.x); b[1] = (short)f2bf(x.y);
      b[2] = (short)f2bf(x.z); b[3] = (short)f2bf(x.w);
      b[4] = (short)f2bf(y.x); b[5] = (short)f2bf(y.y);
      b[6] = (short)f2bf(y.z); b[7] = (short)f2bf(y.w);
      bf1[kb] = b;
    }
  }

  // Per-lane glds source byte-offsets within a row. Issue i: LDS slot
  // (wave*8+i)*1024B + lane*16B = short index s; v=s>>7, blk8'=(s>>3)&15;
  // source blk8 = blk8' ^ (v&15) -> conflict-free MFMA reads later.
  int goff[8];
#pragma unroll
  for (int i = 0; i < 8; i++) {
    int v = wave * 32 + i * 4 + (lane >> 4);
    int kb = l15 ^ (v & 15);
    goff[i] = v * 256 + kb * 16; // bytes
  }
  const char* chunkbase = (const char*)(T16 + (size_t)(chunk * RC) * (NV * ND));

  // stage row 0 into buf 0
#pragma unroll
  for (int i = 0; i < 8; i++)
    glds16(chunkbase + goff[i], &Blds[0][(wave * 8 + i) * 512 + lane * 8]);
  __syncthreads();

  u64 a0[CPC], a1[CPC]; // per-lane top-8 for the two owned queries
#pragma unroll
  for (int i = 0; i < CPC; i++) { a0[i] = 0; a1[i] = 0; }

  const short* abase = &Blds[0][l31 * 128];
  for (int rl = 0; rl < RC; rl++) {
    const int cur = rl & 1;
    if (rl < RC - 1) { // async stage next row into other buffer
      const char* rs = chunkbase + (size_t)(rl + 1) * 32768;
#pragma unroll
      for (int i = 0; i < 8; i++)
        glds16(rs + goff[i], &Blds[1 - cur][(wave * 8 + i) * 512 + lane * 8]);
    }

    float run0 = -3.402823466e+38f, run1 = -3.402823466e+38f;
#pragma unroll
    for (int t = 0; t < 4; t++) {
      floatx16 acc0 = 0, acc1 = 0;
#pragma unroll
      for (int kb = 0; kb < 8; kb++) {
        // A[m=lane&31 -> vector t*32+l31][k=half*8+j]; swizzled block index
        const short* ap = abase + cur * 16384 + t * 4096 +
                          8 * ((kb * 2 + half) ^ (l31 & 15));
        short8 af = *reinterpret_cast<const short8*>(ap);
        acc0 = __builtin_amdgcn_mfma_f32_32x32x16_bf16(af, bf0[kb], acc0, 0, 0, 0);
        acc1 = __builtin_amdgcn_mfma_f32_32x32x16_bf16(af, bf1[kb], acc1, 0, 0, 0);
      }
      run0 = fmaxf(run0, max16(acc0));
      run1 = fmaxf(run1, max16(acc1));
    }
    run0 = fmaxf(run0, __shfl_xor(run0, 32, 64)); // merge the two v-halves
    run1 = fmaxf(run1, __shfl_xor(run1, 32, 64));

    u32 rid = (u32)(chunk * RC + rl);
    insert8(a0, ((u64)key_of(run0) << 32) | rid);
    insert8(a1, ((u64)key_of(run1) << 32) | rid);
    __syncthreads(); // drains glds (issued a full row ago) + guards buffer swap
  }

  if (lane < 32) { // lane owns the two queries; halves are duplicates
    const int q0 = qblock * 256 + wave * 64 + l31;
    u64* dst0 = cand + (size_t)q0 * (NCHUNK * CPC) + chunk * CPC;
    u64* dst1 = dst0 + (size_t)32 * (NCHUNK * CPC);
#pragma unroll
    for (int i = 0; i < CPC; i++) { dst0[i] = a0[i]; dst1[i] = a1[i]; }
  }
}

// ---------------- K2: wave-per-query merge -> top-24 rows + buckets ----------
__global__ void k2_select(const u64* __restrict__ cand, u64* __restrict__ refined,
                          u32* __restrict__ cnt, u32* __restrict__ bucket) {
  const int q = blockIdx.x;
  const int lane = threadIdx.x;
  const u64* base = cand + (size_t)q * (NCHUNK * CPC);
  u64 a[12];
#pragma unroll
  for (int i = 0; i < 12; i++) a[i] = 0;
  for (int i = 0; i < 32; i++) {
    u64 x = base[i * 64 + lane];
    if (x > a[11]) {
#pragma unroll
      for (int p = 0; p < 12; p++) {
        u64 mx = a[p] > x ? a[p] : x;
        u64 mn = a[p] > x ? x : a[p];
        a[p] = mx; x = mn;
      }
    }
  }
  if (lane < CSEL) refined[(size_t)q * CSEL + lane] = 0; // sentinel for K3

  for (int j = 0; j < CSEL; j++) {
    u64 head = a[0];
    u64 W = head;
#pragma unroll
    for (int off = 1; off < 64; off <<= 1) {
      u64 o = __shfl_xor(W, off, 64);
      if (o > W) W = o;
    }
    if (head == W) { // unique winner lane: pop + emit bucket entry
#pragma unroll
      for (int p = 0; p < 11; p++) a[p] = a[p + 1];
      a[11] = 0;
      u32 row = (u32)W & 4095u;
      u32 slot = atomicAdd(cnt + row, 1u);
      if (slot < BCAP) bucket[(size_t)row * BCAP + slot] = ((u32)q << 5) | (u32)j;
    }
  }
}

// ---------------- K3: exact fp32 refine, bucketed by table row ---------------
// Grid 4096 (one WG per row), 512 threads = 4 groups of 128; each group
// processes TWO entries per pass (2 independent fma chains per thread for ILP;
// each LDS float4 read feeds 8 fmas). Row in swizzled LDS (64 KiB); q
// scalarized via readfirstlane -> s_loads. Per-dot fp32 accumulation order is
// strictly sequential (matches ref exactly; batching never mixes chains).
__device__ __forceinline__ void k3_emit(float acc, u32 ent, int row, int v, int lane,
                                        u64* __restrict__ refined) {
  // wave argmax (smaller v wins ties), then global atomicMax
  u64 p = ((u64)key_of(acc) << 32) | (u32)(127 - v);
#pragma unroll
  for (int off = 1; off < 64; off <<= 1) {
    u64 o = __shfl_xor(p, off, 64);
    if (o > p) p = o;
  }
  if (lane == 0) {
    u32 q = ent >> 5, j = ent & 31u;
    u32 vbest = 127u - (u32)(p & 0xFFFFFFFFu);
    u64 packed = ((p >> 32) << 32) | (u32)(row * 128 + vbest);
    atomicMax(reinterpret_cast<unsigned long long*>(&refined[(size_t)q * CSEL + j]), packed);
  }
}

__global__ void k3_refine(const float* __restrict__ Q, const float* __restrict__ table,
                          const u32* __restrict__ cnt, const u32* __restrict__ bucket,
                          u64* __restrict__ refined) {
  __shared__ float rowv[128 * 128]; // float4 chunk d4 of vec v at (d4 ^ (v&31))
  const int row = blockIdx.x;
  const int tid = threadIdx.x; // 0..511
  u32 n = cnt[row];
  if (n > BCAP) n = BCAP;
  if (n == 0) return;
  const float* src = table + (size_t)row * (NV * ND);
#pragma unroll
  for (int i = 0; i < 8; i++) {
    int idx = i * 2048 + tid * 4;
    int v = idx >> 7;
    int d4 = tid & 31;
    *reinterpret_cast<float4*>(&rowv[v * 128 + ((d4 ^ (v & 31)) << 2)]) =
        *reinterpret_cast<const float4*>(src + idx);
  }
  __syncthreads();
  const int g = tid >> 7;   // entry-group 0..3
  const int v = tid & 127;  // vector owned by this thread
  const int lane = tid & 63;
  const int sw = v & 31;
  const u32* bk = bucket + (size_t)row * BCAP;
  for (u32 e0 = (u32)(g * 2); e0 < n; e0 += 8) {
    // clamp OOB second slot to a valid entry; its atomic is guarded below
    u32 ent0 = __builtin_amdgcn_readfirstlane(bk[e0]);
    u32 ent1 = __builtin_amdgcn_readfirstlane(bk[e0 + 1 < n ? e0 + 1 : e0]);
    const float* qp0 = Q + (size_t)(ent0 >> 5) * 128; // uniform -> scalar loads
    const float* qp1 = Q + (size_t)(ent1 >> 5) * 128;
    float c0 = 0.f, c1 = 0.f;
#pragma unroll
    for (int d4 = 0; d4 < 32; d4++) { // strict sequential order per dot
      float4 rv = *reinterpret_cast<const float4*>(&rowv[v * 128 + ((d4 ^ sw) << 2)]);
      c0 = fmaf(rv.x, qp0[d4 * 4 + 0], c0);
      c0 = fmaf(rv.y, qp0[d4 * 4 + 1], c0);
      c0 = fmaf(rv.z, qp0[d4 * 4 + 2], c0);
      c0 = fmaf(rv.w, qp0[d4 * 4 + 3], c0);
      c1 = fmaf(rv.x, qp1[d4 * 4 + 0], c1);
      c1 = fmaf(rv.y, qp1[d4 * 4 + 1], c1);
      c1 = fmaf(rv.z, qp1[d4 * 4 + 2], c1);
      c1 = fmaf(rv.w, qp1[d4 * 4 + 3], c1);
    }
    k3_emit(c0, ent0, row, v, lane, refined);
    if (e0 + 1 < n) k3_emit(c1, ent1, row, v, lane, refined);
  }
}

// ---------------- K4: sort 24 -> top-16, gather values/scores/ids ------------
__global__ void k4_finalize(const float* __restrict__ table, const u64* __restrict__ refined,
                            float* __restrict__ out) {
  __shared__ u64 arr[CSEL];
  __shared__ u32 fids[KTOP];
  __shared__ float scs[KTOP];
  const int q = blockIdx.x;
  const int tid = threadIdx.x;
  if (tid < CSEL) arr[tid] = refined[(size_t)q * CSEL + tid];
  __syncthreads();
  if (tid == 0) {
    for (int i = 1; i < CSEL; i++) { // insertion sort desc = ref order
      u64 x = arr[i]; int p = i;
      while (p > 0 && arr[p - 1] < x) { arr[p] = arr[p - 1]; p--; }
      arr[p] = x;
    }
    for (int i = 0; i < KTOP; i++) {
      fids[i] = (u32)arr[i];
      scs[i] = unkey((u32)(arr[i] >> 32));
    }
  }
  __syncthreads();
  const int i = tid >> 4, sub = tid & 15;
  const float* src = table + (size_t)fids[i] * 128 + sub * 8;
  float* dst = out + ((size_t)q * KTOP + i) * 128 + sub * 8;
  *reinterpret_cast<float4*>(dst) = *reinterpret_cast<const float4*>(src);
  *reinterpret_cast<float4*>(dst + 4) = *reinterpret_cast<const float4*>(src + 4);
  if (tid < KTOP) {
    out[8388608 + (size_t)q * KTOP + tid] = scs[tid];
    out[8388608 + 65536 + (size_t)q * KTOP + tid] = (float)fids[tid];
  }
}

extern "C" void kernel_launch(void* const* d_in, const int* in_sizes, int n_in,
                              void* d_out, int out_size, void* d_ws, size_t ws_size,
                              hipStream_t stream) {
  (void)in_sizes; (void)n_in; (void)out_size; (void)ws_size;
  const float* Q = (const float*)d_in[0];
  const float* T = (const float*)d_in[1];
  float* out = (float*)d_out;
  char* ws = (char*)d_ws;
  // ws layout (total ~209 MiB)
  unsigned short* T16 = (unsigned short*)ws;                                   // 128 MiB
  u64* cand    = (u64*)(ws + 134217728);                                       //  64 MiB
  u32* cnt     = (u32*)(ws + 134217728 + 67108864);                            //  16 KiB
  u32* bucket  = (u32*)(ws + 134217728 + 67108864 + 16384);                    //  16 MiB
  u64* refined = (u64*)(ws + 134217728 + 67108864 + 16384 + 16777216);         // 768 KiB

  hipMemsetAsync(cnt, 0, NR * sizeof(u32), stream);
  k0_convert<<<65536, 256, 0, stream>>>(T, T16);
  k1_coarse<<<dim3(16, 256), 256, 0, stream>>>(Q, T16, cand);
  k2_select<<<NQ, 64, 0, stream>>>(cand, refined, cnt, bucket);
  k3_refine<<<NR, 512, 0, stream>>>(Q, T, cnt, bucket, refined);
  k4_finalize<<<NQ, 256, 0, stream>>>(T, refined, out);
}